// Round 10
// baseline (1485.932 us; speedup 1.0000x reference)
//
#include <hip/hip_runtime.h>
#include <hip/hip_bf16.h>
#include <math.h>

typedef unsigned int uint32;

#define TBINS 1024
#define RMAX  10.4f

__device__ __forceinline__ uint32 pack_bf16(float a, float b){
  __hip_bfloat16 ba = __float2bfloat16(a);
  __hip_bfloat16 bb = __float2bfloat16(b);
  unsigned short ua = *reinterpret_cast<unsigned short*>(&ba);
  unsigned short ub = *reinterpret_cast<unsigned short*>(&bb);
  return (uint32)ua | ((uint32)ub << 16);
}
__device__ __forceinline__ float bf_lo(uint32 u){ return __uint_as_float(u << 16); }
__device__ __forceinline__ float bf_hi(uint32 u){ return __uint_as_float(u & 0xffff0000u); }

// ---------------- dest-CSR: count + scan ----------------

__global__ void k_count(const int* __restrict__ key, int* __restrict__ counts, int E){
  int e = blockIdx.x*256 + threadIdx.x;
  if (e < E) atomicAdd(&counts[key[e]], 1);
}

__global__ void k_scan1(const int* __restrict__ cnt, int* __restrict__ excl,
                        int* __restrict__ bsum, int N){
  __shared__ int sm[1024];
  int tid = threadIdx.x, gid = blockIdx.x*1024 + tid;
  int v = (gid < N) ? cnt[gid] : 0;
  sm[tid] = v; __syncthreads();
  for (int off=1; off<1024; off<<=1){
    int t = (tid >= off) ? sm[tid-off] : 0;
    __syncthreads();
    sm[tid] += t;
    __syncthreads();
  }
  if (gid < N) excl[gid] = sm[tid] - v;
  if (tid == 1023) bsum[blockIdx.x] = sm[tid];
}

__global__ void k_scan2(int* __restrict__ bsum, int NB){
  __shared__ int sm[1024];
  int tid = threadIdx.x;
  int v = (tid < NB) ? bsum[tid] : 0;
  sm[tid] = v; __syncthreads();
  for (int off=1; off<1024; off<<=1){
    int t = (tid >= off) ? sm[tid-off] : 0;
    __syncthreads();
    sm[tid] += t;
    __syncthreads();
  }
  if (tid < NB) bsum[tid] = sm[tid] - v;
}

__global__ void k_scan3(const int* __restrict__ excl, const int* __restrict__ bsum,
                        int* __restrict__ offsets, int N, int E){
  int gid = blockIdx.x*1024 + threadIdx.x;
  if (gid < N) offsets[gid] = excl[gid] + bsum[gid>>10];
  if (gid == N) offsets[N] = E;
}

// ---------------- dest-CSR fill: broadcast-scan, block-owned dest range ----------------
// Each block owns dests [b*R, b*R+R); streams all edst (L2-broadcast), ranks
// matches via LDS cursors, writes csr_src into its OWN contiguous region
// (single-XCD L2-resident -> no sector-writeback amplification).

__global__ __launch_bounds__(1024) void k_build(
    const int* __restrict__ esrc, const int* __restrict__ edst,
    const int* __restrict__ offsets, int* __restrict__ csr_src,
    int N, int E, int R){
  __shared__ int cur[512];
  int base = blockIdx.x * R;
  int hi = base + R; if (hi > N) hi = N;
  int nloc = hi - base;
  if (nloc <= 0) return;
  for (int i = threadIdx.x; i < nloc; i += 1024) cur[i] = offsets[base + i];
  __syncthreads();
  for (int e = threadIdx.x; e < E; e += 1024){
    int d = edst[e];
    if (d >= base && d < hi){
      int p = atomicAdd(&cur[d - base], 1);
      csr_src[p] = __ldg(&esrc[e]);
    }
  }
}

// ---------------- pack pos+type into one float4 ----------------

__global__ void k_pack(const float* __restrict__ pos, const int* __restrict__ types,
                       float4* __restrict__ ptyp, int N){
  int i = blockIdx.x*256 + threadIdx.x;
  if (i >= N) return;
  float4 f; f.x = pos[3*i]; f.y = pos[3*i+1]; f.z = pos[3*i+2]; f.w = __int_as_float(types[i]);
  ptyp[i] = f;
}

// ---------------- radial-MLP evaluation (builder only) ----------------

__device__ __forceinline__ void radial_mlp(
    float r, int td, int ts, const float* sEmb,
    const float* sW1, const float* sW2, float* w_out /*9*/){
  float ee[18];
  #pragma unroll
  for (int i=0;i<4;i++){ ee[i] = sEmb[td*4+i]; ee[4+i] = sEmb[ts*4+i]; }
  float rm = fmaxf(r, 1e-9f);
  float inv = 1.f/rm;
  float xx = r * 0.2f;
  float x2v = xx*xx, x3v = x2v*xx, x6 = x3v*x3v, x7 = x6*xx, x8 = x7*xx;
  float env = 1.f - 28.f*x6 + 48.f*x7 - 21.f*x8;
  const float bc = 0.6324555320336759f;
  float pref = bc * env * inv;
  const float PI = 3.14159265358979323846f;
  float s1, cth;
  __sincosf(PI*xx, &s1, &cth);
  float two_c = 2.f*cth;
  float sp = 0.f, sc = s1;
  ee[8] = pref * sc;
  #pragma unroll
  for (int n=2;n<=10;n++){
    float sn = two_c*sc - sp;
    sp = sc; sc = sn;
    ee[7+n] = pref * sc;
  }
  float h[10];
  #pragma unroll
  for (int j=0;j<10;j++){
    float a = 0.f;
    #pragma unroll
    for (int k=0;k<18;k++) a = fmaf(ee[k], sW1[k*10+j], a);
    h[j] = fmaxf(a, 0.f);
  }
  #pragma unroll
  for (int sj=0;sj<9;sj++){
    float a = 0.f;
    #pragma unroll
    for (int j=0;j<10;j++) a = fmaf(h[j], sW2[j*9+sj], a);
    w_out[sj] = a;
  }
}

// ---------------- build layer-1+2 table: 20 u32/rec = {w1 (v,d)x9, w2 (v,d)x9, pad2} ----------------

__global__ __launch_bounds__(256) void k_mktab12(
    const float* __restrict__ embed,
    const float* __restrict__ w1a, const float* __restrict__ w2a,
    const float* __restrict__ w1b, const float* __restrict__ w2b,
    uint32* __restrict__ tab12){
  __shared__ float sEmb[16];
  __shared__ float sW1a[180], sW2a[90], sW1b[180], sW2b[90];
  int t = threadIdx.x;
  if (t < 16) sEmb[t] = embed[t];
  if (t < 180){ sW1a[t] = w1a[t]; sW1b[t] = w1b[t]; }
  if (t < 90){  sW2a[t] = w2a[t]; sW2b[t] = w2b[t]; }
  __syncthreads();
  int gid = blockIdx.x*256 + t;
  if (gid >= 16*TBINS) return;
  int combo = gid / TBINS, bin = gid - combo*TBINS;
  int td = combo >> 2, ts = combo & 3;
  const float dR = RMAX / TBINS;
  float r0 = bin*dR, r1 = r0 + dR;
  float a0[9], a1[9], b0[9], b1[9];
  radial_mlp(r0, td, ts, sEmb, sW1a, sW2a, a0);
  radial_mlp(r1, td, ts, sEmb, sW1a, sW2a, a1);
  radial_mlp(r0, td, ts, sEmb, sW1b, sW2b, b0);
  radial_mlp(r1, td, ts, sEmb, sW1b, sW2b, b1);
  uint32* rec = tab12 + (size_t)gid*20;
  #pragma unroll
  for (int s=0;s<9;s++){
    rec[s]   = pack_bf16(a0[s], a1[s]-a0[s]);
    rec[9+s] = pack_bf16(b0[s], b1[s]-b0[s]);
  }
  rec[18] = 0u; rec[19] = 0u;
}

// ---------------- build layer-3 table: 12 u32/rec = {(v,d)x9, pad3} ----------------

__global__ __launch_bounds__(256) void k_mktab3(
    const float* __restrict__ embed,
    const float* __restrict__ w1, const float* __restrict__ w2,
    uint32* __restrict__ tab3){
  __shared__ float sEmb[16];
  __shared__ float sW1[180], sW2[90];
  int t = threadIdx.x;
  if (t < 16) sEmb[t] = embed[t];
  if (t < 180) sW1[t] = w1[t];
  if (t < 90)  sW2[t] = w2[t];
  __syncthreads();
  int gid = blockIdx.x*256 + t;
  if (gid >= 16*TBINS) return;
  int combo = gid / TBINS, bin = gid - combo*TBINS;
  int td = combo >> 2, ts = combo & 3;
  const float dR = RMAX / TBINS;
  float r0 = bin*dR, r1 = r0 + dR;
  float a0[9], a1[9];
  radial_mlp(r0, td, ts, sEmb, sW1, sW2, a0);
  radial_mlp(r1, td, ts, sEmb, sW1, sW2, a1);
  uint32* rec = tab3 + (size_t)gid*12;
  #pragma unroll
  for (int s=0;s<9;s++) rec[s] = pack_bf16(a0[s], a1[s]-a0[s]);
  rec[9] = 0u; rec[10] = 0u; rec[11] = 0u;
}

// ---------------- layer 1+2 edge pass with bf16 table: Z->x1, bf16 shw2 store ----------------

__global__ __launch_bounds__(256) void k_layer12t(
    const int* __restrict__ offsets, const int* __restrict__ csr_src,
    const float4* __restrict__ ptyp, const float* __restrict__ embed,
    const uint32* __restrict__ tab12, const float* __restrict__ tp1,
    float* __restrict__ x1, uint32* __restrict__ shwb, int N){
  __shared__ float sT[36*92];
  __shared__ float sEmb[16];
  int t = threadIdx.x;
  if (t < 16) sEmb[t] = embed[t];
  for (int i=t; i<36*92; i+=256) sT[i] = tp1[i]*0.25f;
  __syncthreads();
  int gid = blockIdx.x*256 + t;
  int n = gid >> 2, q = gid & 3;
  if (n >= N) return;
  float4 fd = ptyp[n];
  float dx = fd.x, dy = fd.y, dz = fd.z;
  int td = __float_as_int(fd.w);
  const float c1 = 1.7320508075688772f, c2 = 3.872983346207417f, c2b = 1.118033988749895f;
  const float invD = (float)TBINS / RMAX;
  float Z[36];
  #pragma unroll
  for (int i=0;i<36;i++) Z[i]=0.f;
  int b0 = offsets[n], b1 = offsets[n+1];
  for (int j=b0+q; j<b1; j+=4){
    int s = csr_src[j];
    float4 fs = ptyp[s];
    float px = dx - fs.x, py = dy - fs.y, pz = dz - fs.z;
    int ts_ = __float_as_int(fs.w);
    float r = sqrtf(px*px + py*py + pz*pz);
    float inv = 1.f/fmaxf(r, 1e-9f);
    float ux = px*inv, uy = py*inv, uz = pz*inv;
    float sh[9];
    sh[0]=1.f; sh[1]=c1*uy; sh[2]=c1*uz; sh[3]=c1*ux;
    sh[4]=c2*ux*uy; sh[5]=c2*uy*uz; sh[6]=c2b*(3.f*uz*uz-1.f); sh[7]=c2*ux*uz;
    sh[8]=0.5f*c2*(ux*ux-uy*uy);
    float tt = r * invD;
    int bb = (int)tt; bb = (bb > TBINS-1) ? TBINS-1 : bb;
    float frac = tt - (float)bb;
    const uint32* rec = tab12 + ((size_t)((td*4+ts_)*TBINS + bb))*20;
    uint32 R[20];
    #pragma unroll
    for (int i=0;i<5;i++) *(uint4*)&R[i*4] = *(const uint4*)(rec + i*4);
    float x0[4];
    #pragma unroll
    for (int i=0;i<4;i++) x0[i] = sEmb[ts_*4+i];
    float sw2[9];
    #pragma unroll
    for (int sj=0;sj<9;sj++){
      uint32 ua = R[sj], ub = R[9+sj];
      float w1v = fmaf(frac, bf_hi(ua), bf_lo(ua));
      float w2v = fmaf(frac, bf_hi(ub), bf_lo(ub));
      float s1v = sh[sj]*w1v;
      sw2[sj] = sh[sj]*w2v;
      #pragma unroll
      for (int i=0;i<4;i++) Z[sj*4+i] = fmaf(s1v, x0[i], Z[sj*4+i]);
    }
    uint32* so = shwb + (size_t)j*5;
    so[0]=pack_bf16(sw2[0],sw2[1]); so[1]=pack_bf16(sw2[2],sw2[3]);
    so[2]=pack_bf16(sw2[4],sw2[5]); so[3]=pack_bf16(sw2[6],sw2[7]);
    so[4]=pack_bf16(sw2[8],0.f);
  }
  // butterfly reduce over the 4-lane group
  #pragma unroll
  for (int m=1; m<=2; m<<=1){
    #pragma unroll
    for (int i=0;i<36;i++) Z[i] += __shfl_xor(Z[i], m, 4);
  }
  // lane q writes x1 elements [q*19, q*19+19)
  float* xo = x1 + (size_t)n*76;
  int gi_prev = -1; float ga = 0.f;
  for (int cc=q*19; cc<q*19+19; cc++){
    float v;
    if (cc < 12){
      float y = 0.f;
      #pragma unroll
      for (int p=0;p<36;p++) y = fmaf(Z[p], sT[p*92+cc], y);
      v = (cc<4) ? (fmaxf(y,0.f) + sEmb[td*4+cc]) : fabsf(y);
    } else {
      int j = cc - 12;
      int gi = (j<24) ? (j/3) : (8 + (j-24)/5);
      if (gi != gi_prev){
        float gy = 0.f;
        #pragma unroll
        for (int p=0;p<36;p++) gy = fmaf(Z[p], sT[p*92+12+gi], gy);
        ga = (gi<4 || (gi>=8 && gi<12)) ? fmaxf(gy,0.f) : tanhf(gy);
        gi_prev = gi;
      }
      float y = 0.f;
      #pragma unroll
      for (int p=0;p<36;p++) y = fmaf(Z[p], sT[p*92+28+j], y);
      v = y*ga;
    }
    xo[cc] = v;
  }
}

// ---------------- cast x1 -> bf16 pairs ----------------

__global__ void k_cast(const float* __restrict__ x1, uint32* __restrict__ x1b, int n38){
  int i = blockIdx.x*256 + threadIdx.x;
  if (i >= n38) return;
  float2 f = *(const float2*)&x1[(size_t)i*2];
  x1b[i] = pack_bf16(f.x, f.y);
}

// ---------------- layer 2 stage A: thread-per-(dest, feature-pair), bf16 shw2 ----------------

__global__ __launch_bounds__(256) void k_conv2c(
    const int* __restrict__ offsets, const int* __restrict__ csr_src,
    const uint32* __restrict__ shwb, const uint32* __restrict__ x1b,
    uint32* __restrict__ Z2u, int d0, int dend){
  int g = blockIdx.x*256 + threadIdx.x;
  int dg = g/38;
  int u = g - dg*38;
  int d = d0 + dg;
  if (d >= dend) return;
  float z[9], zb[9];
  #pragma unroll
  for (int s=0;s<9;s++){ z[s]=0.f; zb[s]=0.f; }
  int b0 = offsets[d], b1 = offsets[d+1];
  for (int j=b0;j<b1;j++){
    int sn = csr_src[j];
    uint32 xv = x1b[(size_t)sn*38 + u];
    float xa = bf_lo(xv), xb = bf_hi(xv);
    const uint32* sw = shwb + (size_t)j*5;
    uint32 a0=sw[0], a1=sw[1], a2=sw[2], a3=sw[3], a4=sw[4];
    float w[9];
    w[0]=bf_lo(a0); w[1]=bf_hi(a0); w[2]=bf_lo(a1); w[3]=bf_hi(a1);
    w[4]=bf_lo(a2); w[5]=bf_hi(a2); w[6]=bf_lo(a3); w[7]=bf_hi(a3); w[8]=bf_lo(a4);
    #pragma unroll
    for (int s=0;s<9;s++){
      z[s]  = fmaf(w[s], xa, z[s]);
      zb[s] = fmaf(w[s], xb, zb[s]);
    }
  }
  uint32* zr = Z2u + (size_t)dg*352;
  #pragma unroll
  for (int s=0;s<9;s++) zr[s*38+u] = pack_bf16(z[s], zb[s]);
  if (u < 10) zr[342+u] = 0u;
}

// ---------------- layer 2 stage B: GEMM + gate + residual + fused A = x2.tp3 ----------------

__global__ void k_wprep(const float* __restrict__ tp2, float* __restrict__ W){
  int q = blockIdx.x*256 + threadIdx.x;
  if (q >= 704*96) return;
  int k = q/96, f = q - 96*k;
  W[q] = (k < 684 && f < 92) ? tp2[k*92+f]*0.25f : 0.f;
}

__global__ __launch_bounds__(256) void k_gemm2bA(
    const uint32* __restrict__ Z2u, const float* __restrict__ W,
    const float* __restrict__ x1, const float* __restrict__ tp3,
    float* __restrict__ A, int d0, int dend){
  __shared__ float lz[64][68];
  __shared__ float lw[64][100];
  __shared__ float tl3[684];
  int t = threadIdx.x;
  int mb = blockIdx.x*64;
  int m0 = d0 + mb;
  int tf = t & 31, tg = t >> 5;
  for (int i=t;i<684;i+=256) tl3[i] = tp3[i]*0.25f;
  float acc[8][3];
  #pragma unroll
  for (int a=0;a<8;a++)
    #pragma unroll
    for (int b=0;b<3;b++) acc[a][b]=0.f;
  for (int c=0;c<11;c++){
    #pragma unroll
    for (int j=0;j<4;j++){
      int q = j*256+t; int m = q>>4, u2 = q&15;
      uint2 v = *(const uint2*)&Z2u[(size_t)(mb+m)*352 + c*32 + u2*2];
      float4 fv;
      fv.x = bf_lo(v.x); fv.y = bf_hi(v.x); fv.z = bf_lo(v.y); fv.w = bf_hi(v.y);
      *(float4*)&lz[m][u2*4] = fv;
    }
    #pragma unroll
    for (int j=0;j<6;j++){
      int q = j*256+t; int k = q/24, f4 = q - k*24;
      *(float4*)&lw[k][f4*4] = *(const float4*)&W[(size_t)(c*64+k)*96 + f4*4];
    }
    __syncthreads();
    #pragma unroll 2
    for (int kk=0; kk<64; kk+=4){
      float av[8][4];
      #pragma unroll
      for (int mi=0;mi<8;mi++) *(float4*)av[mi] = *(const float4*)&lz[tg*8+mi][kk];
      #pragma unroll
      for (int u=0;u<4;u++){
        #pragma unroll
        for (int fj=0;fj<3;fj++){
          float bv = lw[kk+u][tf*3+fj];
          #pragma unroll
          for (int mi=0;mi<8;mi++) acc[mi][fj] = fmaf(av[mi][u], bv, acc[mi][fj]);
        }
      }
    }
    __syncthreads();
  }
  #pragma unroll
  for (int mi=0;mi<8;mi++)
    #pragma unroll
    for (int fj=0;fj<3;fj++)
      lw[tg*8+mi][tf*3+fj] = acc[mi][fj];
  __syncthreads();
  int m = t>>2, q = t&3;
  int node = m0 + m;
  float pA[9];
  #pragma unroll
  for (int s=0;s<9;s++) pA[s]=0.f;
  if (node < dend){
    const float* xr = x1 + (size_t)node*76;
    for (int cc=q*19; cc<q*19+19; cc++){
      float v;
      if (cc < 12){
        float y = lw[m][cc];
        v = (cc<4) ? fmaxf(y,0.f) : fabsf(y);
      } else {
        int j = cc-12;
        int gi = (j<24) ? (j/3) : (8 + (j-24)/5);
        float gy = lw[m][12+gi];
        float ga = (gi<4 || (gi>=8 && gi<12)) ? fmaxf(gy,0.f) : tanhf(gy);
        v = lw[m][28+j]*ga;
      }
      float xv = v + xr[cc];            // final x2[node][cc]
      #pragma unroll
      for (int s=0;s<9;s++) pA[s] = fmaf(xv, tl3[s*76+cc], pA[s]);
    }
  }
  // reduce A partials over the 4 lanes of this node
  #pragma unroll
  for (int off=1; off<=2; off<<=1){
    #pragma unroll
    for (int s=0;s<9;s++) pA[s] += __shfl_xor(pA[s], off, 4);
  }
  if (node < dend && q == 0){
    float* Ar = A + (size_t)node*12;
    float4 w0 = {pA[0],pA[1],pA[2],pA[3]};
    float4 w1 = {pA[4],pA[5],pA[6],pA[7]};
    *(float4*)Ar = w0;
    *(float4*)(Ar+4) = w1;
    Ar[8] = pA[8];
  }
}

// ---------------- layer 3: natural edge order, dot(shw3, A[src]) -> out ----------------

__global__ __launch_bounds__(256) void k_edge3(
    const int* __restrict__ esrc, const int* __restrict__ edst,
    const float4* __restrict__ ptyp, const uint32* __restrict__ tab3,
    const float* __restrict__ A, float* __restrict__ out, int E){
  int e = blockIdx.x*256 + threadIdx.x;
  float part = 0.f;
  if (e < E){
    int s = esrc[e], d = edst[e];
    float4 fs = ptyp[s], fd = ptyp[d];
    float px = fd.x-fs.x, py = fd.y-fs.y, pz = fd.z-fs.z;
    int ts_ = __float_as_int(fs.w), td_ = __float_as_int(fd.w);
    float r = sqrtf(px*px + py*py + pz*pz);
    float inv = 1.f/fmaxf(r, 1e-9f);
    float ux = px*inv, uy = py*inv, uz = pz*inv;
    const float c1 = 1.7320508075688772f, c2 = 3.872983346207417f, c2b = 1.118033988749895f;
    float sh[9];
    sh[0]=1.f; sh[1]=c1*uy; sh[2]=c1*uz; sh[3]=c1*ux;
    sh[4]=c2*ux*uy; sh[5]=c2*uy*uz; sh[6]=c2b*(3.f*uz*uz-1.f); sh[7]=c2*ux*uz;
    sh[8]=0.5f*c2*(ux*ux-uy*uy);
    const float invD = (float)TBINS / RMAX;
    float tt = r * invD;
    int bb = (int)tt; bb = (bb > TBINS-1) ? TBINS-1 : bb;
    float frac = tt - (float)bb;
    const uint32* rec = tab3 + ((size_t)((td_*4+ts_)*TBINS + bb))*12;
    uint32 R[12];
    #pragma unroll
    for (int i=0;i<3;i++) *(uint4*)&R[i*4] = *(const uint4*)(rec + i*4);
    const float* Ar = A + (size_t)s*12;
    float4 a0 = *(const float4*)Ar;
    float4 a1 = *(const float4*)(Ar+4);
    float Av[9] = {a0.x,a0.y,a0.z,a0.w,a1.x,a1.y,a1.z,a1.w,Ar[8]};
    #pragma unroll
    for (int sj=0;sj<9;sj++){
      uint32 u = R[sj];
      float w = fmaf(frac, bf_hi(u), bf_lo(u));
      part = fmaf(sh[sj]*w, Av[sj], part);
    }
  }
  #pragma unroll
  for (int off=32; off>0; off>>=1) part += __shfl_down(part, off, 64);
  if ((threadIdx.x & 63) == 0) atomicAdd(out, part);
}

// ---------------- launch ----------------

extern "C" void kernel_launch(void* const* d_in, const int* in_sizes, int n_in,
                              void* d_out, int out_size, void* d_ws, size_t ws_size,
                              hipStream_t stream){
  const int*   types = (const int*)d_in[0];
  const float* pos   = (const float*)d_in[1];
  const int*   esrc  = (const int*)d_in[2];
  const int*   edst  = (const int*)d_in[3];
  const float* embed = (const float*)d_in[4];
  const float* m1w1=(const float*)d_in[5],  *m1w2=(const float*)d_in[6],  *tp1=(const float*)d_in[7];
  const float* m2w1=(const float*)d_in[8],  *m2w2=(const float*)d_in[9],  *tp2=(const float*)d_in[10];
  const float* m3w1=(const float*)d_in[11], *m3w2=(const float*)d_in[12], *tp3=(const float*)d_in[13];
  int N = in_sizes[0];
  int E = in_sizes[2];
  float* out = (float*)d_out;

  char* wsb = (char*)d_ws; size_t off = 0;
  auto alloc = [&](size_t b)->char*{ char* p = wsb + off; off = (off + b + 255) & ~(size_t)255; return p; };
  float*  x1      = (float*)alloc((size_t)N*76*sizeof(float));
  uint32* x1b     = (uint32*)alloc((size_t)N*38*sizeof(uint32));
  float4* ptyp    = (float4*)alloc((size_t)N*sizeof(float4));
  uint32* shwb    = (uint32*)alloc((size_t)E*5*sizeof(uint32));
  int*    csr_src = (int*)alloc((size_t)E*sizeof(int));
  int*    offsets = (int*)alloc((size_t)(N+1)*sizeof(int));
  int*    counts  = (int*)alloc((size_t)N*sizeof(int));
  int*    excl    = (int*)alloc((size_t)N*sizeof(int));
  int*    bsum    = (int*)alloc(1024*sizeof(int));
  float*  Wp      = (float*)alloc((size_t)704*96*sizeof(float));
  float*  A       = (float*)alloc((size_t)N*12*sizeof(float));
  uint32* tab12   = (uint32*)alloc((size_t)16*TBINS*20*sizeof(uint32));
  uint32* tab3    = (uint32*)alloc((size_t)16*TBINS*12*sizeof(uint32));

  // elastic bf16 Z2 chunk
  size_t avail = (ws_size > off) ? (ws_size - off - 512) : 0;
  long long rows = (long long)(avail / (352*sizeof(uint32))) - 64;
  int CH = (rows > 50176) ? 50176 : (int)rows;
  CH = (CH / 64) * 64;
  if (CH < 64) CH = 64;
  uint32* Z2u = (uint32*)alloc((size_t)(CH+64)*352*sizeof(uint32));

  hipMemsetAsync(counts, 0, (size_t)N*sizeof(int), stream);
  hipMemsetAsync(out, 0, sizeof(float), stream);

  int nbE = (E+255)/256;
  int NB1 = (N+1023)/1024;
  int nbN = (N+255)/256;
  int nbT = (16*TBINS+255)/256;
  k_pack<<<nbN,256,0,stream>>>(pos, types, ptyp, N);
  k_mktab12<<<nbT,256,0,stream>>>(embed, m1w1, m1w2, m2w1, m2w2, tab12);
  k_mktab3<<<nbT,256,0,stream>>>(embed, m3w1, m3w2, tab3);
  // dest-CSR: count + scan + broadcast-scan fill
  k_count<<<nbE,256,0,stream>>>(edst, counts, E);
  k_scan1<<<NB1,1024,0,stream>>>(counts, excl, bsum, N);
  k_scan2<<<1,1024,0,stream>>>(bsum, NB1);
  k_scan3<<<(N+1+1023)/1024,1024,0,stream>>>(excl, bsum, offsets, N, E);
  {
    int R = (N + 255) / 256;          // dests per block (<=512 for LDS cursors)
    int nb = (N + R - 1) / R;
    k_build<<<nb,1024,0,stream>>>(esrc, edst, offsets, csr_src, N, E, R);
  }

  k_wprep<<<(704*96+255)/256,256,0,stream>>>(tp2, Wp);

  // layer 1 + layer-2 shw (single fused edge pass, table)
  k_layer12t<<<(4*N+255)/256,256,0,stream>>>(offsets, csr_src, ptyp, embed,
                                             tab12, tp1, x1, shwb, N);
  k_cast<<<(N*38+255)/256,256,0,stream>>>(x1, x1b, N*38);

  // layer 2 (+ fused A epilogue; x2 never materialized)
  for (int d0 = 0; d0 < N; d0 += CH){
    int dend = (d0 + CH < N) ? (d0 + CH) : N;
    int nn = dend - d0;
    k_conv2c<<<((nn*38)+255)/256,256,0,stream>>>(offsets, csr_src, shwb, x1b, Z2u, d0, dend);
    k_gemm2bA<<<(nn+63)/64,256,0,stream>>>(Z2u, Wp, x1, tp3, A, d0, dend);
  }

  // layer 3: per-edge dot with A[src]
  k_edge3<<<nbE,256,0,stream>>>(esrc, edst, ptyp, tab3, A, out, E);
}

// Round 11
// 1040.975 us; speedup vs baseline: 1.4274x; 1.4274x over previous
//
#include <hip/hip_runtime.h>
#include <hip/hip_bf16.h>
#include <math.h>

typedef unsigned int uint32;

#define TBINS 1024
#define RMAX  10.4f
#define BSHIFT 7              // 128 dests per bucket
#define BDR    (1<<BSHIFT)

__device__ __forceinline__ uint32 pack_bf16(float a, float b){
  __hip_bfloat16 ba = __float2bfloat16(a);
  __hip_bfloat16 bb = __float2bfloat16(b);
  unsigned short ua = *reinterpret_cast<unsigned short*>(&ba);
  unsigned short ub = *reinterpret_cast<unsigned short*>(&bb);
  return (uint32)ua | ((uint32)ub << 16);
}
__device__ __forceinline__ float bf_lo(uint32 u){ return __uint_as_float(u << 16); }
__device__ __forceinline__ float bf_hi(uint32 u){ return __uint_as_float(u & 0xffff0000u); }

// ---------------- dest-CSR: count + scan ----------------

__global__ void k_count(const int* __restrict__ key, int* __restrict__ counts, int E){
  int e = blockIdx.x*256 + threadIdx.x;
  if (e < E) atomicAdd(&counts[key[e]], 1);
}

__global__ void k_scan1(const int* __restrict__ cnt, int* __restrict__ excl,
                        int* __restrict__ bsum, int N){
  __shared__ int sm[1024];
  int tid = threadIdx.x, gid = blockIdx.x*1024 + tid;
  int v = (gid < N) ? cnt[gid] : 0;
  sm[tid] = v; __syncthreads();
  for (int off=1; off<1024; off<<=1){
    int t = (tid >= off) ? sm[tid-off] : 0;
    __syncthreads();
    sm[tid] += t;
    __syncthreads();
  }
  if (gid < N) excl[gid] = sm[tid] - v;
  if (tid == 1023) bsum[blockIdx.x] = sm[tid];
}

__global__ void k_scan2(int* __restrict__ bsum, int NB){
  __shared__ int sm[1024];
  int tid = threadIdx.x;
  int v = (tid < NB) ? bsum[tid] : 0;
  sm[tid] = v; __syncthreads();
  for (int off=1; off<1024; off<<=1){
    int t = (tid >= off) ? sm[tid-off] : 0;
    __syncthreads();
    sm[tid] += t;
    __syncthreads();
  }
  if (tid < NB) bsum[tid] = sm[tid] - v;
}

__global__ void k_scan3(const int* __restrict__ excl, const int* __restrict__ bsum,
                        int* __restrict__ offsets, int N, int E){
  int gid = blockIdx.x*1024 + threadIdx.x;
  if (gid < N) offsets[gid] = excl[gid] + bsum[gid>>10];
  if (gid == N) offsets[N] = E;
}

// ---------------- edge counting-sort: bucket cursors ----------------

__global__ void k_curinit(const int* __restrict__ offsets, int* __restrict__ gcur,
                          int N, int NBUCK){
  int b = blockIdx.x*256 + threadIdx.x;
  if (b < NBUCK){
    int d = b << BSHIFT; if (d > N) d = N;
    gcur[b] = offsets[d];
  }
}

// Pass A: chunk-owned blocks; LDS histogram -> one global reservation per
// (block,bucket) -> contiguous pair writes. Each edge read ONCE.
__global__ __launch_bounds__(1024) void k_binA(
    const int* __restrict__ esrc, const int* __restrict__ edst,
    int* __restrict__ gcur, int2* __restrict__ pair, int E, int NBUCK){
  __shared__ int cnt[1024];
  __shared__ int run[1024];
  int tid = threadIdx.x;
  int e0 = blockIdx.x * 8192;
  cnt[tid] = 0;
  __syncthreads();
  #pragma unroll
  for (int k=0;k<8;k++){
    int e = e0 + k*1024 + tid;
    if (e < E) atomicAdd(&cnt[edst[e] >> BSHIFT], 1);
  }
  __syncthreads();
  if (tid < NBUCK && cnt[tid] > 0) run[tid] = atomicAdd(&gcur[tid], cnt[tid]);
  __syncthreads();
  #pragma unroll
  for (int k=0;k<8;k++){
    int e = e0 + k*1024 + tid;
    if (e < E){
      int d = edst[e];
      int p = atomicAdd(&run[d >> BSHIFT], 1);
      int2 pr; pr.x = esrc[e]; pr.y = d;
      pair[p] = pr;
    }
  }
}

// Pass B: bucket-owned blocks; read own pairs (coalesced), exact-rank via
// LDS cursors, write csr_src into own contiguous region.
__global__ __launch_bounds__(256) void k_binB(
    const int2* __restrict__ pair, const int* __restrict__ offsets,
    int* __restrict__ csr_src, int N, int NBUCK){
  __shared__ int cur[BDR];
  int base = blockIdx.x << BSHIFT;
  int hi = base + BDR; if (hi > N) hi = N;
  int nloc = hi - base;
  if (nloc <= 0) return;
  for (int i = threadIdx.x; i < nloc; i += 256) cur[i] = offsets[base + i];
  __syncthreads();
  int p0 = offsets[base], p1 = offsets[hi];
  for (int p = p0 + threadIdx.x; p < p1; p += 256){
    int2 pr = pair[p];
    int slot = atomicAdd(&cur[pr.y - base], 1);
    csr_src[slot] = pr.x;
  }
}

// ---------------- pack pos+type into one float4 ----------------

__global__ void k_pack(const float* __restrict__ pos, const int* __restrict__ types,
                       float4* __restrict__ ptyp, int N){
  int i = blockIdx.x*256 + threadIdx.x;
  if (i >= N) return;
  float4 f; f.x = pos[3*i]; f.y = pos[3*i+1]; f.z = pos[3*i+2]; f.w = __int_as_float(types[i]);
  ptyp[i] = f;
}

// ---------------- radial-MLP evaluation (builder only) ----------------

__device__ __forceinline__ void radial_mlp(
    float r, int td, int ts, const float* sEmb,
    const float* sW1, const float* sW2, float* w_out /*9*/){
  float ee[18];
  #pragma unroll
  for (int i=0;i<4;i++){ ee[i] = sEmb[td*4+i]; ee[4+i] = sEmb[ts*4+i]; }
  float rm = fmaxf(r, 1e-9f);
  float inv = 1.f/rm;
  float xx = r * 0.2f;
  float x2v = xx*xx, x3v = x2v*xx, x6 = x3v*x3v, x7 = x6*xx, x8 = x7*xx;
  float env = 1.f - 28.f*x6 + 48.f*x7 - 21.f*x8;
  const float bc = 0.6324555320336759f;
  float pref = bc * env * inv;
  const float PI = 3.14159265358979323846f;
  float s1, cth;
  __sincosf(PI*xx, &s1, &cth);
  float two_c = 2.f*cth;
  float sp = 0.f, sc = s1;
  ee[8] = pref * sc;
  #pragma unroll
  for (int n=2;n<=10;n++){
    float sn = two_c*sc - sp;
    sp = sc; sc = sn;
    ee[7+n] = pref * sc;
  }
  float h[10];
  #pragma unroll
  for (int j=0;j<10;j++){
    float a = 0.f;
    #pragma unroll
    for (int k=0;k<18;k++) a = fmaf(ee[k], sW1[k*10+j], a);
    h[j] = fmaxf(a, 0.f);
  }
  #pragma unroll
  for (int sj=0;sj<9;sj++){
    float a = 0.f;
    #pragma unroll
    for (int j=0;j<10;j++) a = fmaf(h[j], sW2[j*9+sj], a);
    w_out[sj] = a;
  }
}

// ---------------- build layer-1+2 table: 20 u32/rec ----------------

__global__ __launch_bounds__(256) void k_mktab12(
    const float* __restrict__ embed,
    const float* __restrict__ w1a, const float* __restrict__ w2a,
    const float* __restrict__ w1b, const float* __restrict__ w2b,
    uint32* __restrict__ tab12){
  __shared__ float sEmb[16];
  __shared__ float sW1a[180], sW2a[90], sW1b[180], sW2b[90];
  int t = threadIdx.x;
  if (t < 16) sEmb[t] = embed[t];
  if (t < 180){ sW1a[t] = w1a[t]; sW1b[t] = w1b[t]; }
  if (t < 90){  sW2a[t] = w2a[t]; sW2b[t] = w2b[t]; }
  __syncthreads();
  int gid = blockIdx.x*256 + t;
  if (gid >= 16*TBINS) return;
  int combo = gid / TBINS, bin = gid - combo*TBINS;
  int td = combo >> 2, ts = combo & 3;
  const float dR = RMAX / TBINS;
  float r0 = bin*dR, r1 = r0 + dR;
  float a0[9], a1[9], b0[9], b1[9];
  radial_mlp(r0, td, ts, sEmb, sW1a, sW2a, a0);
  radial_mlp(r1, td, ts, sEmb, sW1a, sW2a, a1);
  radial_mlp(r0, td, ts, sEmb, sW1b, sW2b, b0);
  radial_mlp(r1, td, ts, sEmb, sW1b, sW2b, b1);
  uint32* rec = tab12 + (size_t)gid*20;
  #pragma unroll
  for (int s=0;s<9;s++){
    rec[s]   = pack_bf16(a0[s], a1[s]-a0[s]);
    rec[9+s] = pack_bf16(b0[s], b1[s]-b0[s]);
  }
  rec[18] = 0u; rec[19] = 0u;
}

// ---------------- build layer-3 table: 12 u32/rec ----------------

__global__ __launch_bounds__(256) void k_mktab3(
    const float* __restrict__ embed,
    const float* __restrict__ w1, const float* __restrict__ w2,
    uint32* __restrict__ tab3){
  __shared__ float sEmb[16];
  __shared__ float sW1[180], sW2[90];
  int t = threadIdx.x;
  if (t < 16) sEmb[t] = embed[t];
  if (t < 180) sW1[t] = w1[t];
  if (t < 90)  sW2[t] = w2[t];
  __syncthreads();
  int gid = blockIdx.x*256 + t;
  if (gid >= 16*TBINS) return;
  int combo = gid / TBINS, bin = gid - combo*TBINS;
  int td = combo >> 2, ts = combo & 3;
  const float dR = RMAX / TBINS;
  float r0 = bin*dR, r1 = r0 + dR;
  float a0[9], a1[9];
  radial_mlp(r0, td, ts, sEmb, sW1, sW2, a0);
  radial_mlp(r1, td, ts, sEmb, sW1, sW2, a1);
  uint32* rec = tab3 + (size_t)gid*12;
  #pragma unroll
  for (int s=0;s<9;s++) rec[s] = pack_bf16(a0[s], a1[s]-a0[s]);
  rec[9] = 0u; rec[10] = 0u; rec[11] = 0u;
}

// ---------------- layer 1+2 edge pass with bf16 table ----------------

__global__ __launch_bounds__(256) void k_layer12t(
    const int* __restrict__ offsets, const int* __restrict__ csr_src,
    const float4* __restrict__ ptyp, const float* __restrict__ embed,
    const uint32* __restrict__ tab12, const float* __restrict__ tp1,
    float* __restrict__ x1, uint32* __restrict__ shwb, int N){
  __shared__ float sT[36*92];
  __shared__ float sEmb[16];
  int t = threadIdx.x;
  if (t < 16) sEmb[t] = embed[t];
  for (int i=t; i<36*92; i+=256) sT[i] = tp1[i]*0.25f;
  __syncthreads();
  int gid = blockIdx.x*256 + t;
  int n = gid >> 2, q = gid & 3;
  if (n >= N) return;
  float4 fd = ptyp[n];
  float dx = fd.x, dy = fd.y, dz = fd.z;
  int td = __float_as_int(fd.w);
  const float c1 = 1.7320508075688772f, c2 = 3.872983346207417f, c2b = 1.118033988749895f;
  const float invD = (float)TBINS / RMAX;
  float Z[36];
  #pragma unroll
  for (int i=0;i<36;i++) Z[i]=0.f;
  int b0 = offsets[n], b1 = offsets[n+1];
  for (int j=b0+q; j<b1; j+=4){
    int s = csr_src[j];
    float4 fs = ptyp[s];
    float px = dx - fs.x, py = dy - fs.y, pz = dz - fs.z;
    int ts_ = __float_as_int(fs.w);
    float r = sqrtf(px*px + py*py + pz*pz);
    float inv = 1.f/fmaxf(r, 1e-9f);
    float ux = px*inv, uy = py*inv, uz = pz*inv;
    float sh[9];
    sh[0]=1.f; sh[1]=c1*uy; sh[2]=c1*uz; sh[3]=c1*ux;
    sh[4]=c2*ux*uy; sh[5]=c2*uy*uz; sh[6]=c2b*(3.f*uz*uz-1.f); sh[7]=c2*ux*uz;
    sh[8]=0.5f*c2*(ux*ux-uy*uy);
    float tt = r * invD;
    int bb = (int)tt; bb = (bb > TBINS-1) ? TBINS-1 : bb;
    float frac = tt - (float)bb;
    const uint32* rec = tab12 + ((size_t)((td*4+ts_)*TBINS + bb))*20;
    uint32 R[20];
    #pragma unroll
    for (int i=0;i<5;i++) *(uint4*)&R[i*4] = *(const uint4*)(rec + i*4);
    float x0[4];
    #pragma unroll
    for (int i=0;i<4;i++) x0[i] = sEmb[ts_*4+i];
    float sw2[9];
    #pragma unroll
    for (int sj=0;sj<9;sj++){
      uint32 ua = R[sj], ub = R[9+sj];
      float w1v = fmaf(frac, bf_hi(ua), bf_lo(ua));
      float w2v = fmaf(frac, bf_hi(ub), bf_lo(ub));
      float s1v = sh[sj]*w1v;
      sw2[sj] = sh[sj]*w2v;
      #pragma unroll
      for (int i=0;i<4;i++) Z[sj*4+i] = fmaf(s1v, x0[i], Z[sj*4+i]);
    }
    uint32* so = shwb + (size_t)j*5;
    so[0]=pack_bf16(sw2[0],sw2[1]); so[1]=pack_bf16(sw2[2],sw2[3]);
    so[2]=pack_bf16(sw2[4],sw2[5]); so[3]=pack_bf16(sw2[6],sw2[7]);
    so[4]=pack_bf16(sw2[8],0.f);
  }
  #pragma unroll
  for (int m=1; m<=2; m<<=1){
    #pragma unroll
    for (int i=0;i<36;i++) Z[i] += __shfl_xor(Z[i], m, 4);
  }
  float* xo = x1 + (size_t)n*76;
  int gi_prev = -1; float ga = 0.f;
  for (int cc=q*19; cc<q*19+19; cc++){
    float v;
    if (cc < 12){
      float y = 0.f;
      #pragma unroll
      for (int p=0;p<36;p++) y = fmaf(Z[p], sT[p*92+cc], y);
      v = (cc<4) ? (fmaxf(y,0.f) + sEmb[td*4+cc]) : fabsf(y);
    } else {
      int j = cc - 12;
      int gi = (j<24) ? (j/3) : (8 + (j-24)/5);
      if (gi != gi_prev){
        float gy = 0.f;
        #pragma unroll
        for (int p=0;p<36;p++) gy = fmaf(Z[p], sT[p*92+12+gi], gy);
        ga = (gi<4 || (gi>=8 && gi<12)) ? fmaxf(gy,0.f) : tanhf(gy);
        gi_prev = gi;
      }
      float y = 0.f;
      #pragma unroll
      for (int p=0;p<36;p++) y = fmaf(Z[p], sT[p*92+28+j], y);
      v = y*ga;
    }
    xo[cc] = v;
  }
}

// ---------------- cast x1 -> bf16 pairs ----------------

__global__ void k_cast(const float* __restrict__ x1, uint32* __restrict__ x1b, int n38){
  int i = blockIdx.x*256 + threadIdx.x;
  if (i >= n38) return;
  float2 f = *(const float2*)&x1[(size_t)i*2];
  x1b[i] = pack_bf16(f.x, f.y);
}

// ---------------- layer 2 stage A ----------------

__global__ __launch_bounds__(256) void k_conv2c(
    const int* __restrict__ offsets, const int* __restrict__ csr_src,
    const uint32* __restrict__ shwb, const uint32* __restrict__ x1b,
    uint32* __restrict__ Z2u, int d0, int dend){
  int g = blockIdx.x*256 + threadIdx.x;
  int dg = g/38;
  int u = g - dg*38;
  int d = d0 + dg;
  if (d >= dend) return;
  float z[9], zb[9];
  #pragma unroll
  for (int s=0;s<9;s++){ z[s]=0.f; zb[s]=0.f; }
  int b0 = offsets[d], b1 = offsets[d+1];
  for (int j=b0;j<b1;j++){
    int sn = csr_src[j];
    uint32 xv = x1b[(size_t)sn*38 + u];
    float xa = bf_lo(xv), xb = bf_hi(xv);
    const uint32* sw = shwb + (size_t)j*5;
    uint32 a0=sw[0], a1=sw[1], a2=sw[2], a3=sw[3], a4=sw[4];
    float w[9];
    w[0]=bf_lo(a0); w[1]=bf_hi(a0); w[2]=bf_lo(a1); w[3]=bf_hi(a1);
    w[4]=bf_lo(a2); w[5]=bf_hi(a2); w[6]=bf_lo(a3); w[7]=bf_hi(a3); w[8]=bf_lo(a4);
    #pragma unroll
    for (int s=0;s<9;s++){
      z[s]  = fmaf(w[s], xa, z[s]);
      zb[s] = fmaf(w[s], xb, zb[s]);
    }
  }
  uint32* zr = Z2u + (size_t)dg*352;
  #pragma unroll
  for (int s=0;s<9;s++) zr[s*38+u] = pack_bf16(z[s], zb[s]);
  if (u < 10) zr[342+u] = 0u;
}

// ---------------- layer 2 stage B: GEMM + gate + residual + fused A ----------------

__global__ void k_wprep(const float* __restrict__ tp2, float* __restrict__ W){
  int q = blockIdx.x*256 + threadIdx.x;
  if (q >= 704*96) return;
  int k = q/96, f = q - 96*k;
  W[q] = (k < 684 && f < 92) ? tp2[k*92+f]*0.25f : 0.f;
}

__global__ __launch_bounds__(256) void k_gemm2bA(
    const uint32* __restrict__ Z2u, const float* __restrict__ W,
    const float* __restrict__ x1, const float* __restrict__ tp3,
    float* __restrict__ A, int d0, int dend){
  __shared__ float lz[64][68];
  __shared__ float lw[64][100];
  __shared__ float tl3[684];
  int t = threadIdx.x;
  int mb = blockIdx.x*64;
  int m0 = d0 + mb;
  int tf = t & 31, tg = t >> 5;
  for (int i=t;i<684;i+=256) tl3[i] = tp3[i]*0.25f;
  float acc[8][3];
  #pragma unroll
  for (int a=0;a<8;a++)
    #pragma unroll
    for (int b=0;b<3;b++) acc[a][b]=0.f;
  for (int c=0;c<11;c++){
    #pragma unroll
    for (int j=0;j<4;j++){
      int q = j*256+t; int m = q>>4, u2 = q&15;
      uint2 v = *(const uint2*)&Z2u[(size_t)(mb+m)*352 + c*32 + u2*2];
      float4 fv;
      fv.x = bf_lo(v.x); fv.y = bf_hi(v.x); fv.z = bf_lo(v.y); fv.w = bf_hi(v.y);
      *(float4*)&lz[m][u2*4] = fv;
    }
    #pragma unroll
    for (int j=0;j<6;j++){
      int q = j*256+t; int k = q/24, f4 = q - k*24;
      *(float4*)&lw[k][f4*4] = *(const float4*)&W[(size_t)(c*64+k)*96 + f4*4];
    }
    __syncthreads();
    #pragma unroll 2
    for (int kk=0; kk<64; kk+=4){
      float av[8][4];
      #pragma unroll
      for (int mi=0;mi<8;mi++) *(float4*)av[mi] = *(const float4*)&lz[tg*8+mi][kk];
      #pragma unroll
      for (int u=0;u<4;u++){
        #pragma unroll
        for (int fj=0;fj<3;fj++){
          float bv = lw[kk+u][tf*3+fj];
          #pragma unroll
          for (int mi=0;mi<8;mi++) acc[mi][fj] = fmaf(av[mi][u], bv, acc[mi][fj]);
        }
      }
    }
    __syncthreads();
  }
  #pragma unroll
  for (int mi=0;mi<8;mi++)
    #pragma unroll
    for (int fj=0;fj<3;fj++)
      lw[tg*8+mi][tf*3+fj] = acc[mi][fj];
  __syncthreads();
  int m = t>>2, q = t&3;
  int node = m0 + m;
  float pA[9];
  #pragma unroll
  for (int s=0;s<9;s++) pA[s]=0.f;
  if (node < dend){
    const float* xr = x1 + (size_t)node*76;
    for (int cc=q*19; cc<q*19+19; cc++){
      float v;
      if (cc < 12){
        float y = lw[m][cc];
        v = (cc<4) ? fmaxf(y,0.f) : fabsf(y);
      } else {
        int j = cc-12;
        int gi = (j<24) ? (j/3) : (8 + (j-24)/5);
        float gy = lw[m][12+gi];
        float ga = (gi<4 || (gi>=8 && gi<12)) ? fmaxf(gy,0.f) : tanhf(gy);
        v = lw[m][28+j]*ga;
      }
      float xv = v + xr[cc];            // final x2[node][cc]
      #pragma unroll
      for (int s=0;s<9;s++) pA[s] = fmaf(xv, tl3[s*76+cc], pA[s]);
    }
  }
  #pragma unroll
  for (int off=1; off<=2; off<<=1){
    #pragma unroll
    for (int s=0;s<9;s++) pA[s] += __shfl_xor(pA[s], off, 4);
  }
  if (node < dend && q == 0){
    float* Ar = A + (size_t)node*12;
    float4 w0 = {pA[0],pA[1],pA[2],pA[3]};
    float4 w1 = {pA[4],pA[5],pA[6],pA[7]};
    *(float4*)Ar = w0;
    *(float4*)(Ar+4) = w1;
    Ar[8] = pA[8];
  }
}

// ---------------- layer 3: natural edge order, dot(shw3, A[src]) -> out ----------------

__global__ __launch_bounds__(256) void k_edge3(
    const int* __restrict__ esrc, const int* __restrict__ edst,
    const float4* __restrict__ ptyp, const uint32* __restrict__ tab3,
    const float* __restrict__ A, float* __restrict__ out, int E){
  int e = blockIdx.x*256 + threadIdx.x;
  float part = 0.f;
  if (e < E){
    int s = esrc[e], d = edst[e];
    float4 fs = ptyp[s], fd = ptyp[d];
    float px = fd.x-fs.x, py = fd.y-fs.y, pz = fd.z-fs.z;
    int ts_ = __float_as_int(fs.w), td_ = __float_as_int(fd.w);
    float r = sqrtf(px*px + py*py + pz*pz);
    float inv = 1.f/fmaxf(r, 1e-9f);
    float ux = px*inv, uy = py*inv, uz = pz*inv;
    const float c1 = 1.7320508075688772f, c2 = 3.872983346207417f, c2b = 1.118033988749895f;
    float sh[9];
    sh[0]=1.f; sh[1]=c1*uy; sh[2]=c1*uz; sh[3]=c1*ux;
    sh[4]=c2*ux*uy; sh[5]=c2*uy*uz; sh[6]=c2b*(3.f*uz*uz-1.f); sh[7]=c2*ux*uz;
    sh[8]=0.5f*c2*(ux*ux-uy*uy);
    const float invD = (float)TBINS / RMAX;
    float tt = r * invD;
    int bb = (int)tt; bb = (bb > TBINS-1) ? TBINS-1 : bb;
    float frac = tt - (float)bb;
    const uint32* rec = tab3 + ((size_t)((td_*4+ts_)*TBINS + bb))*12;
    uint32 R[12];
    #pragma unroll
    for (int i=0;i<3;i++) *(uint4*)&R[i*4] = *(const uint4*)(rec + i*4);
    const float* Ar = A + (size_t)s*12;
    float4 a0 = *(const float4*)Ar;
    float4 a1 = *(const float4*)(Ar+4);
    float Av[9] = {a0.x,a0.y,a0.z,a0.w,a1.x,a1.y,a1.z,a1.w,Ar[8]};
    #pragma unroll
    for (int sj=0;sj<9;sj++){
      uint32 u = R[sj];
      float w = fmaf(frac, bf_hi(u), bf_lo(u));
      part = fmaf(sh[sj]*w, Av[sj], part);
    }
  }
  #pragma unroll
  for (int off=32; off>0; off>>=1) part += __shfl_down(part, off, 64);
  if ((threadIdx.x & 63) == 0) atomicAdd(out, part);
}

// ---------------- launch ----------------

extern "C" void kernel_launch(void* const* d_in, const int* in_sizes, int n_in,
                              void* d_out, int out_size, void* d_ws, size_t ws_size,
                              hipStream_t stream){
  const int*   types = (const int*)d_in[0];
  const float* pos   = (const float*)d_in[1];
  const int*   esrc  = (const int*)d_in[2];
  const int*   edst  = (const int*)d_in[3];
  const float* embed = (const float*)d_in[4];
  const float* m1w1=(const float*)d_in[5],  *m1w2=(const float*)d_in[6],  *tp1=(const float*)d_in[7];
  const float* m2w1=(const float*)d_in[8],  *m2w2=(const float*)d_in[9],  *tp2=(const float*)d_in[10];
  const float* m3w1=(const float*)d_in[11], *m3w2=(const float*)d_in[12], *tp3=(const float*)d_in[13];
  int N = in_sizes[0];
  int E = in_sizes[2];
  float* out = (float*)d_out;

  char* wsb = (char*)d_ws; size_t off = 0;
  auto alloc = [&](size_t b)->char*{ char* p = wsb + off; off = (off + b + 255) & ~(size_t)255; return p; };
  float*  x1      = (float*)alloc((size_t)N*76*sizeof(float));
  uint32* x1b     = (uint32*)alloc((size_t)N*38*sizeof(uint32));
  float4* ptyp    = (float4*)alloc((size_t)N*sizeof(float4));
  uint32* shwb    = (uint32*)alloc((size_t)E*5*sizeof(uint32));
  int*    csr_src = (int*)alloc((size_t)E*sizeof(int));
  int2*   pair    = (int2*)alloc((size_t)E*sizeof(int2));
  int*    offsets = (int*)alloc((size_t)(N+1)*sizeof(int));
  int*    counts  = (int*)alloc((size_t)N*sizeof(int));
  int*    excl    = (int*)alloc((size_t)N*sizeof(int));
  int*    bsum    = (int*)alloc(1024*sizeof(int));
  int*    gcur    = (int*)alloc(1024*sizeof(int));
  float*  Wp      = (float*)alloc((size_t)704*96*sizeof(float));
  float*  A       = (float*)alloc((size_t)N*12*sizeof(float));
  uint32* tab12   = (uint32*)alloc((size_t)16*TBINS*20*sizeof(uint32));
  uint32* tab3    = (uint32*)alloc((size_t)16*TBINS*12*sizeof(uint32));

  // elastic bf16 Z2 chunk
  size_t avail = (ws_size > off) ? (ws_size - off - 512) : 0;
  long long rows = (long long)(avail / (352*sizeof(uint32))) - 64;
  int CH = (rows > 50176) ? 50176 : (int)rows;
  CH = (CH / 64) * 64;
  if (CH < 64) CH = 64;
  uint32* Z2u = (uint32*)alloc((size_t)(CH+64)*352*sizeof(uint32));

  hipMemsetAsync(counts, 0, (size_t)N*sizeof(int), stream);
  hipMemsetAsync(out, 0, sizeof(float), stream);

  int nbE = (E+255)/256;
  int NB1 = (N+1023)/1024;
  int nbN = (N+255)/256;
  int nbT = (16*TBINS+255)/256;
  int NBUCK = (N + BDR - 1) >> BSHIFT;       // <=1024 for N<=131072
  k_pack<<<nbN,256,0,stream>>>(pos, types, ptyp, N);
  k_mktab12<<<nbT,256,0,stream>>>(embed, m1w1, m1w2, m2w1, m2w2, tab12);
  k_mktab3<<<nbT,256,0,stream>>>(embed, m3w1, m3w2, tab3);
  // dest-CSR: count + scan + counting-sort fill
  k_count<<<nbE,256,0,stream>>>(edst, counts, E);
  k_scan1<<<NB1,1024,0,stream>>>(counts, excl, bsum, N);
  k_scan2<<<1,1024,0,stream>>>(bsum, NB1);
  k_scan3<<<(N+1+1023)/1024,1024,0,stream>>>(excl, bsum, offsets, N, E);
  k_curinit<<<(NBUCK+255)/256,256,0,stream>>>(offsets, gcur, N, NBUCK);
  k_binA<<<(E+8191)/8192,1024,0,stream>>>(esrc, edst, gcur, pair, E, NBUCK);
  k_binB<<<NBUCK,256,0,stream>>>(pair, offsets, csr_src, N, NBUCK);

  k_wprep<<<(704*96+255)/256,256,0,stream>>>(tp2, Wp);

  // layer 1 + layer-2 shw (single fused edge pass, table)
  k_layer12t<<<(4*N+255)/256,256,0,stream>>>(offsets, csr_src, ptyp, embed,
                                             tab12, tp1, x1, shwb, N);
  k_cast<<<(N*38+255)/256,256,0,stream>>>(x1, x1b, N*38);

  // layer 2 (+ fused A epilogue; x2 never materialized)
  for (int d0 = 0; d0 < N; d0 += CH){
    int dend = (d0 + CH < N) ? (d0 + CH) : N;
    int nn = dend - d0;
    k_conv2c<<<((nn*38)+255)/256,256,0,stream>>>(offsets, csr_src, shwb, x1b, Z2u, d0, dend);
    k_gemm2bA<<<(nn+63)/64,256,0,stream>>>(Z2u, Wp, x1, tp3, A, d0, dend);
  }

  // layer 3: per-edge dot with A[src]
  k_edge3<<<nbE,256,0,stream>>>(esrc, edst, ptyp, tab3, A, out, E);
}